// Round 2
// baseline (718.434 us; speedup 1.0000x reference)
//
#include <hip/hip_runtime.h>

#define THREADS 256
#define WAVES_PB 4      // 256 threads = 4 waves
#define MAX_BLOCKS 8192
// wave-chunk = 1024 OUTPUT elems (dense). worst case chunks:
// 16*8*2048^2/1024 = 524288 -> grid-stride loop (32768 waves, <=16 iters)

// ws layout (uint32):
//  [0..8]   offE : output elem prefix, offE[b] = sum_{j<b} 16*s_j^2
//  [9..17]  csum : chunk prefix, csum[b] = sum_{j<b} ceil(16*s_j^2/1024)
//  [18..25] s[b]
//  [26..33] s2[b]
//  [34..41] inv_s[b]  (float bits)
//  [42..49] inv_s2[b] (float bits)
__global__ void setup_offsets_kernel(const int* __restrict__ seq,
                                     unsigned int* __restrict__ ws) {
    if (threadIdx.x == 0 && blockIdx.x == 0) {
        unsigned int oE = 0, cs = 0;
        ws[0] = 0u; ws[9] = 0u;
        for (int b = 0; b < 8; ++b) {
            unsigned int s    = (unsigned int)seq[b];
            unsigned int s2   = s * s;
            unsigned int nout = s2 << 4;          // 16 * s^2
            oE += nout;
            cs += (nout + 1023u) >> 10;
            ws[1 + b]  = oE;
            ws[10 + b] = cs;
            ws[18 + b] = s;
            ws[26 + b] = s2;
            ((float*)ws)[34 + b] = 1.0f / (float)s;
            ((float*)ws)[42 + b] = 1.0f / (float)s2;
        }
    }
}

__global__ void __launch_bounds__(THREADS)
unpad_mask_kernel(const float* __restrict__ mask,     // fp16 promoted to f32 by harness
                  const unsigned int* __restrict__ ws,
                  int* __restrict__ out) {             // bool output as int32
    __shared__ unsigned int offE[9];
    __shared__ unsigned int csum[9];
    __shared__ unsigned int slen[8];
    __shared__ unsigned int ssq[8];
    __shared__ float        sinv[8];
    __shared__ float        sinv2[8];

    int tx = threadIdx.x;
    if (tx < 9) { offE[tx] = ws[tx]; csum[tx] = ws[9 + tx]; }
    if (tx < 8) {
        slen[tx]  = ws[18 + tx];
        ssq[tx]   = ws[26 + tx];
        sinv[tx]  = ((const float*)ws)[34 + tx];
        sinv2[tx] = ((const float*)ws)[42 + tx];
    }
    __syncthreads();

    unsigned int nchunks     = csum[8];
    unsigned int total_waves = gridDim.x * WAVES_PB;
    unsigned int wave_id     = blockIdx.x * WAVES_PB + ((unsigned int)tx >> 6);
    unsigned int lane        = (unsigned int)tx & 63u;

#pragma unroll 1
    for (unsigned int chunk = wave_id; chunk < nchunks; chunk += total_waves) {
        // batch search over chunk prefix (monotone, wave-uniform)
        unsigned int b = 0;
#pragma unroll
        for (int j = 1; j < 8; ++j) b += (chunk >= csum[j]) ? 1u : 0u;

        unsigned int s    = slen[b];
        unsigned int s2   = ssq[b];
        float        inv  = sinv[b];
        float        inv2 = sinv2[b];
        unsigned int tb   = (chunk - csum[b]) << 10;   // batch-local OUTPUT offset
        unsigned int nout = s2 << 4;
        unsigned int gbase = offE[b] + tb;             // global packed offset (mult of 16)
        const float* mb   = mask + ((size_t)b << 22);

        if (s2 >= 1024u && tb + 1024u <= nout) {
            // ---- fast path: full chunk, single head-boundary max ----
            // wave-uniform: pb = tb mod s2 ((float)tb exact: tb mult of 1024 < 2^26)
            unsigned int h  = (unsigned int)((float)tb * inv2);
            int pbi = (int)tb - (int)(h * s2);
            while (pbi < 0)          pbi += (int)s2;
            while (pbi >= (int)s2)   pbi -= (int)s2;
            unsigned int pb = (unsigned int)pbi;

#pragma unroll
            for (int sub = 0; sub < 4; ++sub) {
                // lane's logical position within the s^2 block
                unsigned int p = pb + ((unsigned int)sub << 8) + (lane << 2);
                if (p >= s2) p -= s2;   // p < 2*s2 guaranteed (offset < 1024 <= s2)

                unsigned int row = (unsigned int)((float)p * inv);
                int col = (int)p - (int)(row * s);
                if (col < 0)            { row -= 1u; col += (int)s; }
                else if (col >= (int)s) { row += 1u; col -= (int)s; }

                unsigned int r0 = row;  int c0 = col;
                float v0 = mb[(size_t)r0 * 2048u + (unsigned int)c0];
                c0++; if (c0 == (int)s) { c0 = 0; r0++; if (r0 == s) r0 = 0u; }
                float v1 = mb[(size_t)r0 * 2048u + (unsigned int)c0];
                c0++; if (c0 == (int)s) { c0 = 0; r0++; if (r0 == s) r0 = 0u; }
                float v2 = mb[(size_t)r0 * 2048u + (unsigned int)c0];
                c0++; if (c0 == (int)s) { c0 = 0; r0++; if (r0 == s) r0 = 0u; }
                float v3 = mb[(size_t)r0 * 2048u + (unsigned int)c0];

                int4 o = make_int4((v0 > 0.5f) ? 1 : 0,
                                   (v1 > 0.5f) ? 1 : 0,
                                   (v2 > 0.5f) ? 1 : 0,
                                   (v3 > 0.5f) ? 1 : 0);
                // DENSE store: consecutive lanes -> consecutive 16B,
                // consecutive chunks -> consecutive 4KB. Fill-like sweep.
                *(int4*)(out + gbase + ((unsigned int)sub << 8) + (lane << 2)) = o;
            }
        } else {
            // ---- generic path: batch tail chunk or tiny s (s2 < 1024) ----
#pragma unroll 1
            for (int sub = 0; sub < 4; ++sub) {
#pragma unroll
                for (int j = 0; j < 4; ++j) {
                    unsigned int eo = ((unsigned int)sub << 8) + (lane << 2) + (unsigned int)j;
                    unsigned int e  = tb + eo;          // batch-local output index
                    if (e >= nout) continue;
                    unsigned int h = (unsigned int)((float)e * inv2);
                    int pi = (int)e - (int)(h * s2);
                    while (pi < 0)        pi += (int)s2;
                    while (pi >= (int)s2) pi -= (int)s2;
                    unsigned int p = (unsigned int)pi;

                    unsigned int row = (unsigned int)((float)p * inv);
                    int col = (int)p - (int)(row * s);
                    if (col < 0)            { row -= 1u; col += (int)s; }
                    else if (col >= (int)s) { row += 1u; col -= (int)s; }

                    float v = mb[(size_t)row * 2048u + (unsigned int)col];
                    out[gbase + eo] = (v > 0.5f) ? 1 : 0;
                }
            }
        }
    }
}

extern "C" void kernel_launch(void* const* d_in, const int* in_sizes, int n_in,
                              void* d_out, int out_size, void* d_ws, size_t ws_size,
                              hipStream_t stream) {
    const float*  mask = (const float*)d_in[0];
    const int*    seq  = (const int*)d_in[1];
    unsigned int* ws   = (unsigned int*)d_ws;   // 50 uints of scratch
    int*          out  = (int*)d_out;

    setup_offsets_kernel<<<1, 64, 0, stream>>>(seq, ws);
    unpad_mask_kernel<<<MAX_BLOCKS, THREADS, 0, stream>>>(mask, ws, out);
}

// Round 3
// 695.867 us; speedup vs baseline: 1.0324x; 1.0324x over previous
//
#include <hip/hip_runtime.h>

#define THREADS 256
#define WAVES_PB 4      // 256 threads = 4 waves
#define MAX_BLOCKS 2048
// region = 4096 SOURCE elems, one wave each, held in 16x int4 registers.
// worst-case regions: 8 * ceil(2048^2/4096) = 8192 = 2048 blocks * 4 waves (1:1)

// ws layout (uint32):
//  [0..8]   offE : output elem prefix, offE[b] = sum_{j<b} 16*s_j^2
//  [9..17]  rsum : region prefix, rsum[b] = sum_{j<b} ceil(s_j^2/4096)
//  [18..25] s[b]
//  [26..33] s2[b]
//  [34..41] inv_s[b] (float bits)
__global__ void setup_offsets_kernel(const int* __restrict__ seq,
                                     unsigned int* __restrict__ ws) {
    if (threadIdx.x == 0 && blockIdx.x == 0) {
        unsigned int oE = 0, rs = 0;
        ws[0] = 0u; ws[9] = 0u;
        for (int b = 0; b < 8; ++b) {
            unsigned int s  = (unsigned int)seq[b];
            unsigned int s2 = s * s;
            oE += s2 << 4;
            rs += (s2 + 4095u) >> 12;
            ws[1 + b]  = oE;
            ws[10 + b] = rs;
            ws[18 + b] = s;
            ws[26 + b] = s2;
            ((float*)ws)[34 + b] = 1.0f / (float)s;
        }
    }
}

__global__ void __launch_bounds__(THREADS)
unpad_mask_kernel(const float* __restrict__ mask,     // fp16 promoted to f32 by harness
                  const unsigned int* __restrict__ ws,
                  int* __restrict__ out) {             // bool output as int32
    __shared__ unsigned int offE[9];
    __shared__ unsigned int rsum[9];
    __shared__ unsigned int slen[8];
    __shared__ unsigned int ssq[8];
    __shared__ float        sinv[8];

    int tx = threadIdx.x;
    if (tx < 9) { offE[tx] = ws[tx]; rsum[tx] = ws[9 + tx]; }
    if (tx < 8) {
        slen[tx] = ws[18 + tx];
        ssq[tx]  = ws[26 + tx];
        sinv[tx] = ((const float*)ws)[34 + tx];
    }
    __syncthreads();

    unsigned int nregions = rsum[8];
    unsigned int region   = blockIdx.x * WAVES_PB + ((unsigned int)tx >> 6);
    unsigned int lane     = (unsigned int)tx & 63u;
    if (region >= nregions) return;

    // batch search (monotone, wave-uniform)
    unsigned int b = 0;
#pragma unroll
    for (int j = 1; j < 8; ++j) b += (region >= rsum[j]) ? 1u : 0u;

    unsigned int s    = slen[b];
    unsigned int s2   = ssq[b];
    float        inv  = sinv[b];
    unsigned int p0   = (region - rsum[b]) << 12;   // batch-local source offset
    unsigned int base = offE[b];
    const float* mb   = mask + ((size_t)b << 22);

    if (p0 + 4096u <= s2) {
        // ---- fast path: full 4096-elem region in registers ----
        int4 o[16];
#pragma unroll
        for (int sub = 0; sub < 16; ++sub) {
            unsigned int p   = p0 + ((unsigned int)sub << 8) + (lane << 2);
            unsigned int row = (unsigned int)((float)p * inv);
            int col = (int)p - (int)(row * s);
            if (col < 0)            { row -= 1u; col += (int)s; }
            else if (col >= (int)s) { row += 1u; col -= (int)s; }

            unsigned int r0 = row;  int c0 = col;
            float v0 = mb[(size_t)r0 * 2048u + (unsigned int)c0];
            c0++; if (c0 == (int)s) { c0 = 0; r0++; }
            float v1 = mb[(size_t)r0 * 2048u + (unsigned int)c0];
            c0++; if (c0 == (int)s) { c0 = 0; r0++; }
            float v2 = mb[(size_t)r0 * 2048u + (unsigned int)c0];
            c0++; if (c0 == (int)s) { c0 = 0; r0++; }
            float v3 = mb[(size_t)r0 * 2048u + (unsigned int)c0];

            o[sub] = make_int4((v0 > 0.5f) ? 1 : 0,
                               (v1 > 0.5f) ? 1 : 0,
                               (v2 > 0.5f) ? 1 : 0,
                               (v3 > 0.5f) ? 1 : 0);
        }

        // ---- heads-OUTER store: one contiguous 16KB run at a time ----
        unsigned int offh = base + p0 + (lane << 2);
        if ((s & 1u) == 0u) {
#pragma unroll
            for (int h = 0; h < 16; ++h) {
#pragma unroll
                for (int sub = 0; sub < 16; ++sub)
                    *(int4*)(out + offh + ((unsigned int)sub << 8)) = o[sub];
                offh += s2;
            }
        } else {
            // odd s: alignment class r = h & 3 (base mult16, p0 mult4096)
#pragma unroll
            for (int h = 0; h < 16; ++h) {
                if ((h & 3) == 0) {
#pragma unroll
                    for (int sub = 0; sub < 16; ++sub)
                        *(int4*)(out + offh + ((unsigned int)sub << 8)) = o[sub];
                } else if ((h & 3) == 2) {
#pragma unroll
                    for (int sub = 0; sub < 16; ++sub) {
                        unsigned int so = offh + ((unsigned int)sub << 8);
                        *(int2*)(out + so)     = make_int2(o[sub].x, o[sub].y);
                        *(int2*)(out + so + 2) = make_int2(o[sub].z, o[sub].w);
                    }
                } else {
#pragma unroll
                    for (int sub = 0; sub < 16; ++sub) {
                        unsigned int so = offh + ((unsigned int)sub << 8);
                        out[so]     = o[sub].x;
                        out[so + 1] = o[sub].y;
                        out[so + 2] = o[sub].z;
                        out[so + 3] = o[sub].w;
                    }
                }
                offh += s2;
            }
        }
    } else {
        // ---- fallback: batch tail region or tiny s ----
#pragma unroll 1
        for (int sub = 0; sub < 16; ++sub) {
            unsigned int sp0 = p0 + ((unsigned int)sub << 8);
            if (sp0 >= s2) break;

            if (s2 - sp0 >= 256u) {
                // full 256-chunk (s >= 16): heads-inner fast-256
                unsigned int q   = sp0 + (lane << 2);
                unsigned int row = (unsigned int)((float)q * inv);
                int col = (int)q - (int)(row * s);
                if (col < 0)            { row -= 1u; col += (int)s; }
                else if (col >= (int)s) { row += 1u; col -= (int)s; }

                unsigned int r0 = row;  int c0 = col;
                float v0 = mb[(size_t)r0 * 2048u + (unsigned int)c0];
                c0++; if (c0 == (int)s) { c0 = 0; r0++; }
                float v1 = mb[(size_t)r0 * 2048u + (unsigned int)c0];
                c0++; if (c0 == (int)s) { c0 = 0; r0++; }
                float v2 = mb[(size_t)r0 * 2048u + (unsigned int)c0];
                c0++; if (c0 == (int)s) { c0 = 0; r0++; }
                float v3 = mb[(size_t)r0 * 2048u + (unsigned int)c0];

                int o0 = (v0 > 0.5f) ? 1 : 0;
                int o1 = (v1 > 0.5f) ? 1 : 0;
                int o2 = (v2 > 0.5f) ? 1 : 0;
                int o3 = (v3 > 0.5f) ? 1 : 0;
                int4 o4  = make_int4(o0, o1, o2, o3);
                int2 o2a = make_int2(o0, o1);
                int2 o2b = make_int2(o2, o3);

                unsigned int off = base + q;
                if ((s & 1u) == 0u) {
#pragma unroll
                    for (int h = 0; h < 16; ++h) {
                        *(int4*)(out + off) = o4;
                        off += s2;
                    }
                } else {
#pragma unroll
                    for (int h = 0; h < 16; ++h) {
                        if ((h & 3) == 0) {
                            *(int4*)(out + off) = o4;
                        } else if ((h & 3) == 2) {
                            *(int2*)(out + off)     = o2a;
                            *(int2*)(out + off + 2) = o2b;
                        } else {
                            out[off]     = o0;
                            out[off + 1] = o1;
                            out[off + 2] = o2;
                            out[off + 3] = o3;
                        }
                        off += s2;
                    }
                }
            } else {
                // partial tail chunk or tiny s: per-element
#pragma unroll
                for (int j = 0; j < 4; ++j) {
                    unsigned int p = sp0 + (lane << 2) + (unsigned int)j;
                    if (p >= s2) continue;
                    unsigned int row = (unsigned int)((float)p * inv);
                    int col = (int)p - (int)(row * s);
                    if (col < 0)            { row -= 1u; col += (int)s; }
                    else if (col >= (int)s) { row += 1u; col -= (int)s; }
                    float v = mb[(size_t)row * 2048u + (unsigned int)col];
                    int o = (v > 0.5f) ? 1 : 0;
                    unsigned int off = base + p;
#pragma unroll
                    for (int h = 0; h < 16; ++h) {
                        out[off] = o;
                        off += s2;
                    }
                }
            }
        }
    }
}

extern "C" void kernel_launch(void* const* d_in, const int* in_sizes, int n_in,
                              void* d_out, int out_size, void* d_ws, size_t ws_size,
                              hipStream_t stream) {
    const float*  mask = (const float*)d_in[0];
    const int*    seq  = (const int*)d_in[1];
    unsigned int* ws   = (unsigned int*)d_ws;   // 42 uints of scratch
    int*          out  = (int*)d_out;

    setup_offsets_kernel<<<1, 64, 0, stream>>>(seq, ws);
    unpad_mask_kernel<<<MAX_BLOCKS, THREADS, 0, stream>>>(mask, ws, out);
}

// Round 4
// 662.697 us; speedup vs baseline: 1.0841x; 1.0501x over previous
//
#include <hip/hip_runtime.h>

#define THREADS 256
#define WAVES_PB 4      // 256 threads = 4 waves
#define ITERS 2         // strided chunks per wave
// chunk = 1024 src elems. worst case: 8 * ceil(2048^2/1024) = 32768
// capacity: 4096 blocks * 4 waves * 2 iters = 32768
#define MAX_BLOCKS 4096

// ws layout (uint32):
//  [0..8]   off16 : output prefix, off16[b] = sum_{j<b} 16*s_j^2
//  [9..17]  csum  : chunk prefix, csum[b] = sum_{j<b} ceil(s_j^2/1024)
//  [18..25] s[b]
//  [26..33] s2[b]
//  [34..41] inv_s[b] (float bits)
__global__ void setup_offsets_kernel(const int* __restrict__ seq,
                                     unsigned int* __restrict__ ws) {
    if (threadIdx.x == 0 && blockIdx.x == 0) {
        unsigned int o16 = 0, cs = 0;
        ws[0] = 0u; ws[9] = 0u;
        for (int b = 0; b < 8; ++b) {
            unsigned int s  = (unsigned int)seq[b];
            unsigned int s2 = s * s;
            o16 += 16u * s2;
            cs  += (s2 + 1023u) >> 10;
            ws[1 + b]  = o16;
            ws[10 + b] = cs;
            ws[18 + b] = s;
            ws[26 + b] = s2;
            ((float*)ws)[34 + b] = 1.0f / (float)s;
        }
    }
}

// For odd-s heads with shift SIG = 4-(h&3):
//  - aligned int4 groups cover chunk elems [SIG, 1020+SIG), lane l sub k group
//    value VV[k], addr offh + k*256 + SIG  (lane 63 skips k=3: group 255 invalid)
//  - leading elems [0,SIG) scalar by lane 0; tail [1020+SIG,1024) scalar by lane 63
#define STORE_SHIFT(VV, SIG) do {                                              \
    *(int4*)(out + offh + 0   + (SIG)) = VV[0];                                \
    *(int4*)(out + offh + 256 + (SIG)) = VV[1];                                \
    *(int4*)(out + offh + 512 + (SIG)) = VV[2];                                \
    if (lane < 63u) *(int4*)(out + offh + 768 + (SIG)) = VV[3];                \
    if (lane == 0u) {                                                          \
        out[habase] = o[0].x;                                                  \
        if ((SIG) >= 2) out[habase + 1] = o[0].y;                              \
        if ((SIG) == 3) out[habase + 2] = o[0].z;                              \
    }                                                                          \
    if (lane == 63u) {                                                         \
        if ((SIG) == 1) out[habase + 1021] = o[3].y;                           \
        if ((SIG) <= 2) out[habase + 1022] = o[3].z;                           \
        out[habase + 1023] = o[3].w;                                           \
    }                                                                          \
} while (0)

__global__ void __launch_bounds__(THREADS)
unpad_mask_kernel(const float* __restrict__ mask,     // fp16 promoted to f32 by harness
                  const unsigned int* __restrict__ ws,
                  int* __restrict__ out) {             // bool output as int32
    __shared__ unsigned int off16[9];
    __shared__ unsigned int csum[9];
    __shared__ unsigned int slen[8];
    __shared__ unsigned int ssq[8];
    __shared__ float        sinv[8];

    int tx = threadIdx.x;
    if (tx < 9) { off16[tx] = ws[tx]; csum[tx] = ws[9 + tx]; }
    if (tx < 8) {
        slen[tx] = ws[18 + tx];
        ssq[tx]  = ws[26 + tx];
        sinv[tx] = ((const float*)ws)[34 + tx];
    }
    __syncthreads();

    unsigned int nchunks     = csum[8];
    unsigned int total_waves = gridDim.x * WAVES_PB;
    unsigned int wave_id     = blockIdx.x * WAVES_PB + ((unsigned int)tx >> 6);
    unsigned int lane        = (unsigned int)tx & 63u;

#pragma unroll 1
    for (int it = 0; it < ITERS; ++it) {
        unsigned int chunk = wave_id + (unsigned int)it * total_waves;
        if (chunk >= nchunks) break;

        // batch search over chunk prefix (monotone, wave-uniform)
        unsigned int b = 0;
#pragma unroll
        for (int j = 1; j < 8; ++j) b += (chunk >= csum[j]) ? 1u : 0u;

        unsigned int s    = slen[b];
        unsigned int s2   = ssq[b];
        float        inv  = sinv[b];
        unsigned int p0   = (chunk - csum[b]) << 10;   // batch-local, mult of 1024
        unsigned int base = off16[b];
        const float* mb   = mask + ((size_t)b << 22);

        if (s2 - p0 >= 1024u) {
            // ---- fast path: full chunk (s >= 32) ----
            // Phase 1: read-once into registers. Lane's flat elems per sub:
            // 256*sub + 4*lane + {0..3}
            unsigned int q0 = p0 + (lane << 2);
            int4 o[4];
#pragma unroll
            for (int sub = 0; sub < 4; ++sub) {
                unsigned int q   = q0 + ((unsigned int)sub << 8);
                unsigned int row = (unsigned int)((float)q * inv);
                int col = (int)q - (int)(row * s);
                if (col < 0)            { row -= 1u; col += (int)s; }
                else if (col >= (int)s) { row += 1u; col -= (int)s; }

                unsigned int r0 = row;  int c0 = col;
                float v0 = mb[(size_t)r0 * 2048u + (unsigned int)c0];
                c0++; if (c0 == (int)s) { c0 = 0; r0++; }
                float v1 = mb[(size_t)r0 * 2048u + (unsigned int)c0];
                c0++; if (c0 == (int)s) { c0 = 0; r0++; }
                float v2 = mb[(size_t)r0 * 2048u + (unsigned int)c0];
                c0++; if (c0 == (int)s) { c0 = 0; r0++; }
                float v3 = mb[(size_t)r0 * 2048u + (unsigned int)c0];

                o[sub] = make_int4((v0 > 0.5f) ? 1 : 0,
                                   (v1 > 0.5f) ? 1 : 0,
                                   (v2 > 0.5f) ? 1 : 0,
                                   (v3 > 0.5f) ? 1 : 0);
            }

            if ((s & 1u) == 0u) {
                // ---- even s: all heads 16B-aligned (s2 mult of 4) ----
                unsigned int off = base + q0;
#pragma unroll
                for (int h = 0; h < 16; ++h) {
                    *(int4*)(out + off)       = o[0];
                    *(int4*)(out + off + 256) = o[1];
                    *(int4*)(out + off + 512) = o[2];
                    *(int4*)(out + off + 768) = o[3];
                    off += s2;
                }
            } else {
                // ---- odd s: rotation-aligned int4 stores ----
                // Neighbor flat int4 of (sub, lane) is (sub, lane+1), and for
                // lane 63 it is (sub+1, lane 0). Export-select + shfl:
                int src = ((int)lane + 1) & 63;
                int sel = (lane == 0u) ? 1 : 0;
                int e0x = sel ? o[1].x : o[0].x;
                int e0y = sel ? o[1].y : o[0].y;
                int e0z = sel ? o[1].z : o[0].z;
                int e1x = sel ? o[2].x : o[1].x;
                int e1y = sel ? o[2].y : o[1].y;
                int e1z = sel ? o[2].z : o[1].z;
                int e2x = sel ? o[3].x : o[2].x;
                int e2y = sel ? o[3].y : o[2].y;
                int e2z = sel ? o[3].z : o[2].z;
                // sub=3 export: lane 0's value only consumed by lane 63,
                // which skips its sub-3 group -> plain o[3] is fine.
                int n0x = __shfl(e0x, src, 64), n0y = __shfl(e0y, src, 64), n0z = __shfl(e0z, src, 64);
                int n1x = __shfl(e1x, src, 64), n1y = __shfl(e1y, src, 64), n1z = __shfl(e1z, src, 64);
                int n2x = __shfl(e2x, src, 64), n2y = __shfl(e2y, src, 64), n2z = __shfl(e2z, src, 64);
                int n3x = __shfl(o[3].x, src, 64), n3y = __shfl(o[3].y, src, 64), n3z = __shfl(o[3].z, src, 64);

                // shifted int4 views of the flat 1024-elem block
                int4 v1[4], v2[4], v3[4];
                v1[0] = make_int4(o[0].y, o[0].z, o[0].w, n0x);
                v1[1] = make_int4(o[1].y, o[1].z, o[1].w, n1x);
                v1[2] = make_int4(o[2].y, o[2].z, o[2].w, n2x);
                v1[3] = make_int4(o[3].y, o[3].z, o[3].w, n3x);
                v2[0] = make_int4(o[0].z, o[0].w, n0x, n0y);
                v2[1] = make_int4(o[1].z, o[1].w, n1x, n1y);
                v2[2] = make_int4(o[2].z, o[2].w, n2x, n2y);
                v2[3] = make_int4(o[3].z, o[3].w, n3x, n3y);
                v3[0] = make_int4(o[0].w, n0x, n0y, n0z);
                v3[1] = make_int4(o[1].w, n1x, n1y, n1z);
                v3[2] = make_int4(o[2].w, n2x, n2y, n2z);
                v3[3] = make_int4(o[3].w, n3x, n3y, n3z);

                unsigned int habase = base + p0;   // wave-uniform head base, += s2
#pragma unroll
                for (int h = 0; h < 16; ++h) {
                    unsigned int offh = habase + (lane << 2);
                    const int r0c = h & 3;         // compile-time under unroll
                    if (r0c == 0) {
                        *(int4*)(out + offh)       = o[0];
                        *(int4*)(out + offh + 256) = o[1];
                        *(int4*)(out + offh + 512) = o[2];
                        *(int4*)(out + offh + 768) = o[3];
                    } else if (r0c == 1) {
                        STORE_SHIFT(v3, 3);
                    } else if (r0c == 2) {
                        STORE_SHIFT(v2, 2);
                    } else {
                        STORE_SHIFT(v1, 1);
                    }
                    habase += s2;
                }
            }
        } else {
            // ---- fallback: partial tail chunk or tiny s ----
#pragma unroll 1
            for (int sub = 0; sub < 4; ++sub) {
                unsigned int sp0 = p0 + ((unsigned int)sub << 8);
                if (sp0 >= s2) break;

                if (s2 - sp0 >= 256u) {
                    unsigned int q   = sp0 + (lane << 2);
                    unsigned int row = (unsigned int)((float)q * inv);
                    int col = (int)q - (int)(row * s);
                    if (col < 0)            { row -= 1u; col += (int)s; }
                    else if (col >= (int)s) { row += 1u; col -= (int)s; }

                    unsigned int r0 = row;  int c0 = col;
                    float v0 = mb[(size_t)r0 * 2048u + (unsigned int)c0];
                    c0++; if (c0 == (int)s) { c0 = 0; r0++; }
                    float v1 = mb[(size_t)r0 * 2048u + (unsigned int)c0];
                    c0++; if (c0 == (int)s) { c0 = 0; r0++; }
                    float v2 = mb[(size_t)r0 * 2048u + (unsigned int)c0];
                    c0++; if (c0 == (int)s) { c0 = 0; r0++; }
                    float v3 = mb[(size_t)r0 * 2048u + (unsigned int)c0];

                    int o0 = (v0 > 0.5f) ? 1 : 0;
                    int o1 = (v1 > 0.5f) ? 1 : 0;
                    int o2 = (v2 > 0.5f) ? 1 : 0;
                    int o3 = (v3 > 0.5f) ? 1 : 0;
                    int4 o4  = make_int4(o0, o1, o2, o3);
                    int2 o2a = make_int2(o0, o1);
                    int2 o2b = make_int2(o2, o3);

                    unsigned int off = base + q;
                    if ((s & 1u) == 0u) {
#pragma unroll
                        for (int h = 0; h < 16; ++h) {
                            *(int4*)(out + off) = o4;
                            off += s2;
                        }
                    } else {
#pragma unroll
                        for (int h = 0; h < 16; ++h) {
                            if ((h & 3) == 0) {
                                *(int4*)(out + off) = o4;
                            } else if ((h & 3) == 2) {
                                *(int2*)(out + off)     = o2a;
                                *(int2*)(out + off + 2) = o2b;
                            } else {
                                out[off]     = o0;
                                out[off + 1] = o1;
                                out[off + 2] = o2;
                                out[off + 3] = o3;
                            }
                            off += s2;
                        }
                    }
                } else {
                    // partial tail chunk or tiny s: per-element
#pragma unroll
                    for (int j = 0; j < 4; ++j) {
                        unsigned int p = sp0 + (lane << 2) + (unsigned int)j;
                        if (p >= s2) continue;
                        unsigned int row = (unsigned int)((float)p * inv);
                        int col = (int)p - (int)(row * s);
                        if (col < 0)            { row -= 1u; col += (int)s; }
                        else if (col >= (int)s) { row += 1u; col -= (int)s; }
                        float v = mb[(size_t)row * 2048u + (unsigned int)col];
                        int o = (v > 0.5f) ? 1 : 0;
                        unsigned int off = base + p;
#pragma unroll
                        for (int h = 0; h < 16; ++h) {
                            out[off] = o;
                            off += s2;
                        }
                    }
                }
            }
        }
    }
}

extern "C" void kernel_launch(void* const* d_in, const int* in_sizes, int n_in,
                              void* d_out, int out_size, void* d_ws, size_t ws_size,
                              hipStream_t stream) {
    const float*  mask = (const float*)d_in[0];
    const int*    seq  = (const int*)d_in[1];
    unsigned int* ws   = (unsigned int*)d_ws;   // 42 uints of scratch
    int*          out  = (int*)d_out;

    setup_offsets_kernel<<<1, 64, 0, stream>>>(seq, ws);
    unpad_mask_kernel<<<MAX_BLOCKS, THREADS, 0, stream>>>(mask, ws, out);
}